// Round 1
// baseline (184.964 us; speedup 1.0000x reference)
//
#include <hip/hip_runtime.h>
#include <hip/hip_bf16.h>
#include <math.h>

#define B_ 4
#define T_ 2048
#define C_ 1024
#define H_ 128
#define RCHUNK 128                 // rows per stats chunk == scores t-tile
#define NCHUNK (T_ / RCHUNK)       // 16 chunks
#define NSCH 32                    // number of 64-wide s-chunks (T/64)

typedef unsigned short u16;
typedef unsigned int   u32;
typedef short short8  __attribute__((ext_vector_type(8)));  // 8 bf16 = 4 VGPRs
typedef short short4v __attribute__((ext_vector_type(4)));  // 8B
typedef float floatx4 __attribute__((ext_vector_type(4)));  // MFMA C/D

// fp32 -> bf16 RNE via hardware cvt (v_cvt_pk_bf16_f32), not bit-twiddle
__device__ __forceinline__ u16 f2bf(float f) {
    __hip_bfloat16 h = __float2bfloat16(f);
    union { __hip_bfloat16 h; u16 u; } v; v.h = h; return v.u;
}
// bf16 -> fp32
__device__ __forceinline__ float bf2f(u16 h) {
    union { u32 u; float f; } v; v.u = ((u32)h) << 16;
    return v.f;
}

// ---------------------------------------------------------------------------
// Kernel A1: W [C][H] fp32 -> Wt [3][H][C] bf16 (transposed for MFMA B-frags).
// ---------------------------------------------------------------------------
__global__ __launch_bounds__(256) void convert_w_kernel(
    const float* __restrict__ Wq, const float* __restrict__ Wk,
    const float* __restrict__ Wv, u16* __restrict__ Wt)
{
    const int k0 = blockIdx.x * 64, n0 = blockIdx.y * 64, widx = blockIdx.z;
    const float* W = (widx == 0) ? Wq : (widx == 1) ? Wk : Wv;

    __shared__ float ts[64][68];                // +4 pad
    for (int i = threadIdx.x; i < 64 * 16; i += 256) {
        int r = i >> 4, c4 = i & 15;
        float4 v = *(const float4*)&W[(size_t)(k0 + r) * H_ + n0 + c4 * 4];
        ts[r][c4 * 4 + 0] = v.x; ts[r][c4 * 4 + 1] = v.y;
        ts[r][c4 * 4 + 2] = v.z; ts[r][c4 * 4 + 3] = v.w;
    }
    __syncthreads();
    for (int i = threadIdx.x; i < 64 * 16; i += 256) {
        int n = i >> 4, k4 = i & 15;
        short4v o;
        #pragma unroll
        for (int j = 0; j < 4; ++j) o[j] = (short)f2bf(ts[k4 * 4 + j][n]);
        *(short4v*)&Wt[(size_t)widx * H_ * C_ + (size_t)(n0 + n) * C_ + k0 + k4 * 4] = o;
    }
}

// ---------------------------------------------------------------------------
// Kernel A2 (MFMA): QKV projection, A staged straight from fp32 x with
// in-register bf16 conversion.  grid (M/64, 3); block 256 = 4 waves;
// tile 64(m) x 128(n); BK=128.  widx 0/1 -> Q,K row-major; widx 2 -> V
// stored TRANSPOSED directly (C/D gives 4 consecutive t per lane).
// ---------------------------------------------------------------------------
__global__ __launch_bounds__(256) void qkv_gemm_kernel(
    const float* __restrict__ x, const u16* __restrict__ Wt,
    u16* __restrict__ Qb, u16* __restrict__ Kb, u16* __restrict__ Vt)
{
    const int m0   = blockIdx.x * 64;
    const int widx = blockIdx.y;
    const u16* Wg = Wt + (size_t)widx * H_ * C_;

    __shared__ u16 As[64 * 136];                // 17.4 KB
    __shared__ u16 Bs[128 * 136];               // 34.8 KB

    const int w    = threadIdx.x >> 6;          // wave -> m rows [16w,16w+16)
    const int lane = threadIdx.x & 63;
    const int q    = lane >> 4, r = lane & 15;

    floatx4 acc[8] = {};                        // 16(m) x 128(n)

    for (int k0 = 0; k0 < C_; k0 += 128) {
        for (int i = threadIdx.x; i < 64 * 16; i += 256) {
            int rr = i >> 4, c = i & 15;
            const float* xg = &x[(size_t)(m0 + rr) * C_ + k0 + c * 8];
            float4 a = *(const float4*)xg;
            float4 b = *(const float4*)(xg + 4);
            short8 o;
            o[0]=(short)f2bf(a.x); o[1]=(short)f2bf(a.y);
            o[2]=(short)f2bf(a.z); o[3]=(short)f2bf(a.w);
            o[4]=(short)f2bf(b.x); o[5]=(short)f2bf(b.y);
            o[6]=(short)f2bf(b.z); o[7]=(short)f2bf(b.w);
            *(short8*)&As[rr * 136 + c * 8] = o;
        }
        for (int i = threadIdx.x; i < 128 * 16; i += 256) {
            int rr = i >> 4, c = i & 15;
            *(float4*)&Bs[rr * 136 + c * 8] =
                *(const float4*)&Wg[(size_t)rr * C_ + k0 + c * 8];
        }
        __syncthreads();

        #pragma unroll
        for (int kk = 0; kk < 4; ++kk) {
            short8 af = *(const short8*)&As[(16 * w + r) * 136 + kk * 32 + q * 8];
            #pragma unroll
            for (int nt = 0; nt < 8; ++nt) {
                short8 bf = *(const short8*)&Bs[(16 * nt + r) * 136 + kk * 32 + q * 8];
                acc[nt] = __builtin_amdgcn_mfma_f32_16x16x32_bf16(af, bf, acc[nt], 0, 0, 0);
            }
        }
        __syncthreads();
    }

    if (widx == 2) {
        const int bb  = m0 / T_;                // 64-row tile never spans b
        const int tt0 = (m0 - bb * T_) + 16 * w + q * 4;
        #pragma unroll
        for (int nt = 0; nt < 8; ++nt) {
            short4v o;
            #pragma unroll
            for (int reg = 0; reg < 4; ++reg) o[reg] = (short)f2bf(acc[nt][reg]);
            *(short4v*)&Vt[((size_t)bb * H_ + 16 * nt + r) * T_ + tt0] = o;
        }
    } else {
        u16* dst = (widx == 0) ? Qb : Kb;
        #pragma unroll
        for (int nt = 0; nt < 8; ++nt)
            #pragma unroll
            for (int reg = 0; reg < 4; ++reg) {
                int mm = m0 + 16 * w + q * 4 + reg;     // C/D row map
                int nn = 16 * nt + r;                   // C/D col map
                dst[(size_t)mm * H_ + nn] = f2bf(acc[nt][reg]);
            }
    }
}

// ---------------------------------------------------------------------------
// Kernel B1 (MFMA, fused stats): 128x128 tile of S = scale * Q·K^T (lower
// triangle).  NEW: instead of raw scores, stores E' = exp(S - M_chunk)
// (masked entries -> 0) as BF16 in chunk-tiled layout S3[b][s/64][t][64].
// Column stats per 128-row chunk: pm = M_chunk (scaled max), pl = sum of
// exp(S - M_chunk) over valid rows.  out_kernel recovers the true softmax
// as P = E' * f[s], f = exp(M_chunk - M_global)/L_global -- so out's inner
// loop needs NO exp and NO causal mask.
// Phases: (1) per-thread-group raw max -> redm; (2a) tid<128 combine ->
// M_chunk (pm + Mrow smem); (3) single exp pass from accumulators feeding
// both the E' tile and per-group sums redl; (2b) tid<128 sum -> pl.
// ---------------------------------------------------------------------------
__global__ __launch_bounds__(256) void scores_kernel(
    const u16* __restrict__ Qb, const u16* __restrict__ Kb,
    u16* __restrict__ S, float* __restrict__ pm, float* __restrict__ pl)
{
    const int si = blockIdx.x;                  // 0..15 (s tile, 128 wide)
    const int ti = blockIdx.y;                  // 0..15 (t tile, 128 tall)
    const int b  = blockIdx.z;
    if (si > ti) return;                        // strictly-upper tiles unused
    const int t0 = ti * 128, s0 = si * 128;
    const bool diag = (si == ti);               // tile touches the diagonal

    __shared__ u16 smem[2 * 128 * 136];         // 69.6 KB: Qs | Ks, then reused
    u16* Qs = smem;
    u16* Ks = smem + 128 * 136;

    const u16* Qg = Qb + ((size_t)b * T_ + t0) * H_;
    const u16* Kg = Kb + ((size_t)b * T_ + s0) * H_;

    for (int i = threadIdx.x; i < 128 * 16; i += 256) {
        int rr = i >> 4, c = i & 15;
        *(float4*)&Qs[rr * 136 + c * 8] = *(const float4*)&Qg[(size_t)rr * H_ + c * 8];
        *(float4*)&Ks[rr * 136 + c * 8] = *(const float4*)&Kg[(size_t)rr * H_ + c * 8];
    }
    __syncthreads();

    const int w    = threadIdx.x >> 6;          // wave -> t rows [32w,32w+32)
    const int lane = threadIdx.x & 63;
    const int q    = lane >> 4, r = lane & 15;

    floatx4 acc[2][8] = {};                     // [m-tile][n-tile] 32t x 128s
    #pragma unroll
    for (int kk = 0; kk < 4; ++kk) {
        short8 a0 = *(const short8*)&Qs[(32 * w +      r) * 136 + kk * 32 + q * 8];
        short8 a1 = *(const short8*)&Qs[(32 * w + 16 + r) * 136 + kk * 32 + q * 8];
        #pragma unroll
        for (int nt = 0; nt < 8; ++nt) {
            short8 bf = *(const short8*)&Ks[(16 * nt + r) * 136 + kk * 32 + q * 8];
            acc[0][nt] = __builtin_amdgcn_mfma_f32_16x16x32_bf16(a0, bf, acc[0][nt], 0, 0, 0);
            acc[1][nt] = __builtin_amdgcn_mfma_f32_16x16x32_bf16(a1, bf, acc[1][nt], 0, 0, 0);
        }
    }
    __syncthreads();                            // everyone done with Qs/Ks

    // ---- reuse smem: bf16 E' tile [128][136] + reduction arrays ---------
    u16*   tile = smem;                         // 34.8 KB
    float* redm = (float*)(smem + 128 * 136);   // [16][128] = 8 KB
    float* redl = redm + 16 * 128;              // [16][128] = 8 KB
    float* Mrow = redl + 16 * 128;              // [128]     = 0.5 KB

    const float scale = 0.08838834764831845f;   // 1/sqrt(128)

    // phase 1: per-thread-group raw column max from accumulators
    #pragma unroll
    for (int nt = 0; nt < 8; ++nt) {
        const int sl = 16 * nt + r;             // local col (C/D col map)
        float mx = -INFINITY;
        #pragma unroll
        for (int mt = 0; mt < 2; ++mt)
            #pragma unroll
            for (int reg = 0; reg < 4; ++reg) {
                const int tl = 32 * w + 16 * mt + q * 4 + reg;
                const bool vl = (!diag) || (tl >= sl);
                mx = fmaxf(mx, vl ? acc[mt][nt][reg] : -INFINITY);
            }
        redm[(4 * w + q) * 128 + sl] = mx;
    }
    __syncthreads();

    // phase 2a: combine 16 row-groups -> scaled chunk max M; publish pm+Mrow
    if (threadIdx.x < 128) {
        const int c = threadIdx.x;
        float M = -INFINITY;
        #pragma unroll
        for (int g = 0; g < 16; ++g) M = fmaxf(M, redm[g * 128 + c]);
        M *= scale;
        Mrow[c] = M;
        pm[((size_t)b * NCHUNK + ti) * T_ + s0 + c] = M;
    }
    __syncthreads();

    // phase 3: single exp pass -> E' tile + per-group sums
    #pragma unroll
    for (int nt = 0; nt < 8; ++nt) {
        const int sl = 16 * nt + r;
        const float M = Mrow[sl];
        float sm = 0.f;
        #pragma unroll
        for (int mt = 0; mt < 2; ++mt)
            #pragma unroll
            for (int reg = 0; reg < 4; ++reg) {
                const int tl = 32 * w + 16 * mt + q * 4 + reg;
                const bool vl = (!diag) || (tl >= sl);
                const float e = vl ? __expf(acc[mt][nt][reg] * scale - M) : 0.f;
                sm += e;
                tile[tl * 136 + sl] = f2bf(e);
            }
        redl[(4 * w + q) * 128 + sl] = sm;
    }
    __syncthreads();

    // phase 2b: L = plain sum of group sums (all relative to same M) -> pl
    if (threadIdx.x < 128) {
        const int c = threadIdx.x;
        float L = 0.f;
        #pragma unroll
        for (int g = 0; g < 16; ++g) L += redl[g * 128 + c];
        pl[((size_t)b * NCHUNK + ti) * T_ + s0 + c] = L;
    }

    // two contiguous 16 KB chunk stores: S3[b][2si+cc][t0..t0+128)[0..64)
    for (int i = threadIdx.x; i < 128 * 16; i += 256) {
        int tl = i >> 4, cc = (i >> 3) & 1, c8 = i & 7;
        u16* Sg = S + (((size_t)b * NSCH + 2 * si + cc) * T_ + t0 + tl) * 64;
        *(float4*)&Sg[c8 * 8] = *(float4*)&tile[tl * 136 + cc * 64 + c8 * 8];
    }
}

// ---------------------------------------------------------------------------
// Kernel B3 (MFMA, register-resident, pipelined, 8-way split-s): out = P @ V,
// P = E'[t,s] * f[s] with E' = exp(S-M_chunk) (mask already baked in as 0)
// and f = exp(M_chunk - M_global)/L_global.  The per-column f row for this
// block's chunk ti is computed in a prologue from pm/pl into LDS (this
// replaces the old stats_reduce kernel -> one fewer dispatch), so the inner
// loop is just bf16->f32, one mul, and a hardware cvt back to bf16 -- no
// exp, no compare/cndmask.
// Block = 512 thr = 8 waves, one 16-row t-tile; wave w handles chunks
// ci ≡ w (mod 8); ci+8's S prefetched into registers while ci computes.
// Padded (stride-132) LDS reduction to avoid 4-way bank conflicts.
// ---------------------------------------------------------------------------
#define RST 132
__global__ __launch_bounds__(512) void out_kernel(
    const u16* __restrict__ S, const u16* __restrict__ Vt,
    const float* __restrict__ pm, const float* __restrict__ pl,
    float* __restrict__ out)
{
    const int b  = blockIdx.y;
    const int tb = (int)(gridDim.x - 1 - blockIdx.x); // heavy tiles first
    const int t0 = tb * 16;
    const int ti = t0 >> 7;                           // this block's t-chunk
    const int nchunks = (t0 + 79) >> 6;               // s0 <= t0+15

    const int w    = threadIdx.x >> 6;                // 0..7: chunk split
    const int lane = threadIdx.x & 63;
    const int q    = lane >> 4, r = lane & 15;
    const int t    = t0 + r;                          // this lane's A row

    const u16* SB  = S  + (size_t)b * NSCH * T_ * 64;
    const u16* VtB = Vt + (size_t)b * H_ * T_;

    __shared__ float fs[T_];                          // 8 KB column factors
    __shared__ float red[8][16 * RST];                // 67.6 KB, padded rows

    floatx4 acc[8] = {};
    short8 sc[2];

    int ci = w;
    if (ci < nchunks) {                               // issue first S loads
        const u16* Sc = SB + ((size_t)ci * T_ + t) * 64;  // (hide under prologue)
        sc[0] = *(const short8*)&Sc[q * 8];
        sc[1] = *(const short8*)&Sc[32 + q * 8];
    }

    // ---- prologue (was stats_reduce): f[s] = exp(pm[ti][s]-M[s]) / L[s] --
    const int smax = 64 * nchunks;
    const float* pmB = pm + (size_t)b * NCHUNK * T_;
    const float* plB = pl + (size_t)b * NCHUNK * T_;
    for (int s = threadIdx.x; s < smax; s += 512) {
        const int c0 = s >> 7;                        // first chunk with t>=s
        float M = -INFINITY;
        for (int c = c0; c < NCHUNK; ++c)
            M = fmaxf(M, pmB[(size_t)c * T_ + s]);
        float L = 0.f;
        for (int c = c0; c < NCHUNK; ++c) {
            const float lg = plB[(size_t)c * T_ + s];
            if (lg > 0.f) L += lg * __expf(pmB[(size_t)c * T_ + s] - M);
        }
        fs[s] = (ti >= c0) ? __expf(pmB[(size_t)ti * T_ + s] - M) / L : 0.f;
    }
    __syncthreads();

    while (ci < nchunks) {
        const int s0 = ci * 64;
        const int cn = ci + 8;

        short8 sn[2];
        if (cn < nchunks) {                           // prefetch next chunk
            const u16* Sc = SB + ((size_t)cn * T_ + t) * 64;
            sn[0] = *(const short8*)&Sc[q * 8];
            sn[1] = *(const short8*)&Sc[32 + q * 8];
        }

        #pragma unroll
        for (int kk = 0; kk < 2; ++kk) {
            const int sb = s0 + kk * 32 + q * 8;      // global s base
            float fv[8];
            *(float4*)&fv[0] = *(const float4*)&fs[sb];
            *(float4*)&fv[4] = *(const float4*)&fs[sb + 4];

            short8 af;                                // P = E' * f  (no exp!)
            #pragma unroll
            for (int j = 0; j < 8; ++j)
                af[j] = (short)f2bf(bf2f((u16)sc[kk][j]) * fv[j]);

            #pragma unroll
            for (int nt = 0; nt < 8; ++nt) {
                short8 bf = *(const short8*)&VtB[(size_t)(16 * nt + r) * T_ + sb];
                acc[nt] = __builtin_amdgcn_mfma_f32_16x16x32_bf16(af, bf, acc[nt], 0, 0, 0);
            }
        }

        sc[0] = sn[0];                                // rotate pipeline regs
        sc[1] = sn[1];
        ci = cn;
    }

    #pragma unroll
    for (int nt = 0; nt < 8; ++nt)
        #pragma unroll
        for (int reg = 0; reg < 4; ++reg)
            red[w][(q * 4 + reg) * RST + 16 * nt + r] = acc[nt][reg];
    __syncthreads();

    float* outB = out + ((size_t)b * T_ + t0) * H_;
    for (int i = threadIdx.x; i < 16 * 128; i += 512) {
        const int row = i >> 7, col = i & 127;
        float sum = 0.f;
        #pragma unroll
        for (int g = 0; g < 8; ++g) sum += red[g][row * RST + col];
        outB[i] = sum;
    }
}

// ---------------------------------------------------------------------------
extern "C" void kernel_launch(void* const* d_in, const int* in_sizes, int n_in,
                              void* d_out, int out_size, void* d_ws, size_t ws_size,
                              hipStream_t stream) {
    const float* x  = (const float*)d_in[0];
    const float* Wq = (const float*)d_in[1];
    const float* Wk = (const float*)d_in[2];
    const float* Wv = (const float*)d_in[3];
    float* out = (float*)d_out;

    // workspace: S3 bf16 [B][32][T][64] (32 MB), Wt, Qb, Kb, Vt, pm, pl.
    // pm/pl moved here (out_kernel reads them while writing d_out).
    u16*   Sb   = (u16*)d_ws;                          // 32 MB
    u16*   Wt   = Sb + (size_t)B_ * T_ * T_;           // 0.75 MB
    u16*   Qb   = Wt + (size_t)3 * H_ * C_;            // 2 MB
    u16*   Kb   = Qb + (size_t)B_ * T_ * H_;           // 2 MB
    u16*   Vt   = Kb + (size_t)B_ * T_ * H_;           // 2 MB
    float* pm   = (float*)(Vt + (size_t)B_ * T_ * H_); // 0.5 MB
    float* pl   = pm + (size_t)B_ * NCHUNK * T_;       // 0.5 MB
    // total ~40 MB

    convert_w_kernel <<<dim3(C_ / 64, H_ / 64, 3), dim3(256), 0, stream>>>(Wq, Wk, Wv, Wt);
    qkv_gemm_kernel  <<<dim3(B_ * T_ / 64, 3),     dim3(256), 0, stream>>>(x, Wt, Qb, Kb, Vt);
    scores_kernel    <<<dim3(16, 16, B_),          dim3(256), 0, stream>>>(Qb, Kb, Sb, pm, pl);
    out_kernel       <<<dim3(T_ / 16, B_),         dim3(512), 0, stream>>>(Sb, Vt, pm, pl, out);
}

// Round 3
// 174.809 us; speedup vs baseline: 1.0581x; 1.0581x over previous
//
#include <hip/hip_runtime.h>
#include <hip/hip_bf16.h>
#include <math.h>

#define B_ 4
#define T_ 2048
#define C_ 1024
#define H_ 128
#define RCHUNK 128                 // rows per stats chunk == scores t-tile
#define NCHUNK (T_ / RCHUNK)       // 16 chunks
#define NSCH 32                    // number of 64-wide s-chunks (T/64)

typedef unsigned short u16;
typedef unsigned int   u32;
typedef short short8  __attribute__((ext_vector_type(8)));  // 8 bf16 = 4 VGPRs
typedef short short4v __attribute__((ext_vector_type(4)));  // 8B
typedef float floatx4 __attribute__((ext_vector_type(4)));  // MFMA C/D

// fp32 -> bf16 RNE via hardware cvt (v_cvt_pk_bf16_f32), not bit-twiddle
__device__ __forceinline__ u16 f2bf(float f) {
    __hip_bfloat16 h = __float2bfloat16(f);
    union { __hip_bfloat16 h; u16 u; } v; v.h = h; return v.u;
}
// bf16 -> fp32
__device__ __forceinline__ float bf2f(u16 h) {
    union { u32 u; float f; } v; v.u = ((u32)h) << 16;
    return v.f;
}

// ---------------------------------------------------------------------------
// Kernel A1: W [C][H] fp32 -> Wt [3][H][C] bf16 (transposed for MFMA B-frags).
// ---------------------------------------------------------------------------
__global__ __launch_bounds__(256) void convert_w_kernel(
    const float* __restrict__ Wq, const float* __restrict__ Wk,
    const float* __restrict__ Wv, u16* __restrict__ Wt)
{
    const int k0 = blockIdx.x * 64, n0 = blockIdx.y * 64, widx = blockIdx.z;
    const float* W = (widx == 0) ? Wq : (widx == 1) ? Wk : Wv;

    __shared__ float ts[64][68];                // +4 pad
    for (int i = threadIdx.x; i < 64 * 16; i += 256) {
        int r = i >> 4, c4 = i & 15;
        float4 v = *(const float4*)&W[(size_t)(k0 + r) * H_ + n0 + c4 * 4];
        ts[r][c4 * 4 + 0] = v.x; ts[r][c4 * 4 + 1] = v.y;
        ts[r][c4 * 4 + 2] = v.z; ts[r][c4 * 4 + 3] = v.w;
    }
    __syncthreads();
    for (int i = threadIdx.x; i < 64 * 16; i += 256) {
        int n = i >> 4, k4 = i & 15;
        short4v o;
        #pragma unroll
        for (int j = 0; j < 4; ++j) o[j] = (short)f2bf(ts[k4 * 4 + j][n]);
        *(short4v*)&Wt[(size_t)widx * H_ * C_ + (size_t)(n0 + n) * C_ + k0 + k4 * 4] = o;
    }
}

// ---------------------------------------------------------------------------
// Kernel A2 (MFMA): QKV projection, A staged straight from fp32 x with
// in-register bf16 conversion.  grid (M/64, 3); block 256 = 4 waves;
// tile 64(m) x 128(n); BK=128.  widx 0/1 -> Q,K row-major; widx 2 -> V
// stored TRANSPOSED directly (C/D gives 4 consecutive t per lane).
// ---------------------------------------------------------------------------
__global__ __launch_bounds__(256) void qkv_gemm_kernel(
    const float* __restrict__ x, const u16* __restrict__ Wt,
    u16* __restrict__ Qb, u16* __restrict__ Kb, u16* __restrict__ Vt)
{
    const int m0   = blockIdx.x * 64;
    const int widx = blockIdx.y;
    const u16* Wg = Wt + (size_t)widx * H_ * C_;

    __shared__ u16 As[64 * 136];                // 17.4 KB
    __shared__ u16 Bs[128 * 136];               // 34.8 KB

    const int w    = threadIdx.x >> 6;          // wave -> m rows [16w,16w+16)
    const int lane = threadIdx.x & 63;
    const int q    = lane >> 4, r = lane & 15;

    floatx4 acc[8] = {};                        // 16(m) x 128(n)

    for (int k0 = 0; k0 < C_; k0 += 128) {
        for (int i = threadIdx.x; i < 64 * 16; i += 256) {
            int rr = i >> 4, c = i & 15;
            const float* xg = &x[(size_t)(m0 + rr) * C_ + k0 + c * 8];
            float4 a = *(const float4*)xg;
            float4 b = *(const float4*)(xg + 4);
            short8 o;
            o[0]=(short)f2bf(a.x); o[1]=(short)f2bf(a.y);
            o[2]=(short)f2bf(a.z); o[3]=(short)f2bf(a.w);
            o[4]=(short)f2bf(b.x); o[5]=(short)f2bf(b.y);
            o[6]=(short)f2bf(b.z); o[7]=(short)f2bf(b.w);
            *(short8*)&As[rr * 136 + c * 8] = o;
        }
        for (int i = threadIdx.x; i < 128 * 16; i += 256) {
            int rr = i >> 4, c = i & 15;
            *(float4*)&Bs[rr * 136 + c * 8] =
                *(const float4*)&Wg[(size_t)rr * C_ + k0 + c * 8];
        }
        __syncthreads();

        #pragma unroll
        for (int kk = 0; kk < 4; ++kk) {
            short8 af = *(const short8*)&As[(16 * w + r) * 136 + kk * 32 + q * 8];
            #pragma unroll
            for (int nt = 0; nt < 8; ++nt) {
                short8 bf = *(const short8*)&Bs[(16 * nt + r) * 136 + kk * 32 + q * 8];
                acc[nt] = __builtin_amdgcn_mfma_f32_16x16x32_bf16(af, bf, acc[nt], 0, 0, 0);
            }
        }
        __syncthreads();
    }

    if (widx == 2) {
        const int bb  = m0 / T_;                // 64-row tile never spans b
        const int tt0 = (m0 - bb * T_) + 16 * w + q * 4;
        #pragma unroll
        for (int nt = 0; nt < 8; ++nt) {
            short4v o;
            #pragma unroll
            for (int reg = 0; reg < 4; ++reg) o[reg] = (short)f2bf(acc[nt][reg]);
            *(short4v*)&Vt[((size_t)bb * H_ + 16 * nt + r) * T_ + tt0] = o;
        }
    } else {
        u16* dst = (widx == 0) ? Qb : Kb;
        #pragma unroll
        for (int nt = 0; nt < 8; ++nt)
            #pragma unroll
            for (int reg = 0; reg < 4; ++reg) {
                int mm = m0 + 16 * w + q * 4 + reg;     // C/D row map
                int nn = 16 * nt + r;                   // C/D col map
                dst[(size_t)mm * H_ + nn] = f2bf(acc[nt][reg]);
            }
    }
}

// ---------------------------------------------------------------------------
// Kernel B1 (MFMA, fused stats): 128x128 tile of S = scale * Q·K^T (lower
// triangle).  Stores E' = exp(S - M_chunk) (masked entries -> 0) as BF16 in
// chunk-tiled layout S3[b][s/64][t][64].  Column stats per 128-row chunk:
// pm = M_chunk (scaled max), pl = sum of exp(S - M_chunk) over valid rows.
// ---------------------------------------------------------------------------
__global__ __launch_bounds__(256) void scores_kernel(
    const u16* __restrict__ Qb, const u16* __restrict__ Kb,
    u16* __restrict__ S, float* __restrict__ pm, float* __restrict__ pl)
{
    const int si = blockIdx.x;                  // 0..15 (s tile, 128 wide)
    const int ti = blockIdx.y;                  // 0..15 (t tile, 128 tall)
    const int b  = blockIdx.z;
    if (si > ti) return;                        // strictly-upper tiles unused
    const int t0 = ti * 128, s0 = si * 128;
    const bool diag = (si == ti);               // tile touches the diagonal

    __shared__ u16 smem[2 * 128 * 136];         // 69.6 KB: Qs | Ks, then reused
    u16* Qs = smem;
    u16* Ks = smem + 128 * 136;

    const u16* Qg = Qb + ((size_t)b * T_ + t0) * H_;
    const u16* Kg = Kb + ((size_t)b * T_ + s0) * H_;

    for (int i = threadIdx.x; i < 128 * 16; i += 256) {
        int rr = i >> 4, c = i & 15;
        *(float4*)&Qs[rr * 136 + c * 8] = *(const float4*)&Qg[(size_t)rr * H_ + c * 8];
        *(float4*)&Ks[rr * 136 + c * 8] = *(const float4*)&Kg[(size_t)rr * H_ + c * 8];
    }
    __syncthreads();

    const int w    = threadIdx.x >> 6;          // wave -> t rows [32w,32w+32)
    const int lane = threadIdx.x & 63;
    const int q    = lane >> 4, r = lane & 15;

    floatx4 acc[2][8] = {};                     // [m-tile][n-tile] 32t x 128s
    #pragma unroll
    for (int kk = 0; kk < 4; ++kk) {
        short8 a0 = *(const short8*)&Qs[(32 * w +      r) * 136 + kk * 32 + q * 8];
        short8 a1 = *(const short8*)&Qs[(32 * w + 16 + r) * 136 + kk * 32 + q * 8];
        #pragma unroll
        for (int nt = 0; nt < 8; ++nt) {
            short8 bf = *(const short8*)&Ks[(16 * nt + r) * 136 + kk * 32 + q * 8];
            acc[0][nt] = __builtin_amdgcn_mfma_f32_16x16x32_bf16(a0, bf, acc[0][nt], 0, 0, 0);
            acc[1][nt] = __builtin_amdgcn_mfma_f32_16x16x32_bf16(a1, bf, acc[1][nt], 0, 0, 0);
        }
    }
    __syncthreads();                            // everyone done with Qs/Ks

    // ---- reuse smem: bf16 E' tile [128][136] + reduction arrays ---------
    u16*   tile = smem;                         // 34.8 KB
    float* redm = (float*)(smem + 128 * 136);   // [16][128] = 8 KB
    float* redl = redm + 16 * 128;              // [16][128] = 8 KB
    float* Mrow = redl + 16 * 128;              // [128]     = 0.5 KB

    const float scale = 0.08838834764831845f;   // 1/sqrt(128)

    // phase 1: per-thread-group raw column max from accumulators
    #pragma unroll
    for (int nt = 0; nt < 8; ++nt) {
        const int sl = 16 * nt + r;             // local col (C/D col map)
        float mx = -INFINITY;
        #pragma unroll
        for (int mt = 0; mt < 2; ++mt)
            #pragma unroll
            for (int reg = 0; reg < 4; ++reg) {
                const int tl = 32 * w + 16 * mt + q * 4 + reg;
                const bool vl = (!diag) || (tl >= sl);
                mx = fmaxf(mx, vl ? acc[mt][nt][reg] : -INFINITY);
            }
        redm[(4 * w + q) * 128 + sl] = mx;
    }
    __syncthreads();

    // phase 2a: combine 16 row-groups -> scaled chunk max M; publish pm+Mrow
    if (threadIdx.x < 128) {
        const int c = threadIdx.x;
        float M = -INFINITY;
        #pragma unroll
        for (int g = 0; g < 16; ++g) M = fmaxf(M, redm[g * 128 + c]);
        M *= scale;
        Mrow[c] = M;
        pm[((size_t)b * NCHUNK + ti) * T_ + s0 + c] = M;
    }
    __syncthreads();

    // phase 3: single exp pass -> E' tile + per-group sums
    #pragma unroll
    for (int nt = 0; nt < 8; ++nt) {
        const int sl = 16 * nt + r;
        const float M = Mrow[sl];
        float sm = 0.f;
        #pragma unroll
        for (int mt = 0; mt < 2; ++mt)
            #pragma unroll
            for (int reg = 0; reg < 4; ++reg) {
                const int tl = 32 * w + 16 * mt + q * 4 + reg;
                const bool vl = (!diag) || (tl >= sl);
                const float e = vl ? __expf(acc[mt][nt][reg] * scale - M) : 0.f;
                sm += e;
                tile[tl * 136 + sl] = f2bf(e);
            }
        redl[(4 * w + q) * 128 + sl] = sm;
    }
    __syncthreads();

    // phase 2b: L = plain sum of group sums (all relative to same M) -> pl
    if (threadIdx.x < 128) {
        const int c = threadIdx.x;
        float L = 0.f;
        #pragma unroll
        for (int g = 0; g < 16; ++g) L += redl[g * 128 + c];
        pl[((size_t)b * NCHUNK + ti) * T_ + s0 + c] = L;
    }

    // two contiguous 16 KB chunk stores: S3[b][2si+cc][t0..t0+128)[0..64)
    for (int i = threadIdx.x; i < 128 * 16; i += 256) {
        int tl = i >> 4, cc = (i >> 3) & 1, c8 = i & 7;
        u16* Sg = S + (((size_t)b * NSCH + 2 * si + cc) * T_ + t0 + tl) * 64;
        *(float4*)&Sg[c8 * 8] = *(float4*)&tile[tl * 136 + cc * 64 + c8 * 8];
    }
}

// ---------------------------------------------------------------------------
// Kernel B2: cook the full factor table ONCE (was being recomputed by all
// 512 out-blocks -> 61 us latency-bound prologue).  For each (b,s):
//   M[s] = max_c pm[c][s],  L[s] = sum_c pl[c][s]*exp(pm[c][s]-M)
//   F[b][c][s] = exp(pm[c][s]-M[s]) / L[s]   (0 for chunks below diagonal)
// 32 blocks; the serial chunk-load chain is paid once per (b,s).
// ---------------------------------------------------------------------------
__global__ __launch_bounds__(256) void stats_f_kernel(
    const float* __restrict__ pm, const float* __restrict__ pl,
    float* __restrict__ F)
{
    const int idx = blockIdx.x * 256 + threadIdx.x;   // b*T + s
    const int b = idx >> 11, s = idx & (T_ - 1);
    const int c0 = s >> 7;                            // first chunk with t>=s
    const float* pmB = pm + (size_t)b * NCHUNK * T_;
    const float* plB = pl + (size_t)b * NCHUNK * T_;

    float M = -INFINITY;
    for (int c = c0; c < NCHUNK; ++c)
        M = fmaxf(M, pmB[(size_t)c * T_ + s]);
    float L = 0.f;
    for (int c = c0; c < NCHUNK; ++c) {
        const float lg = plB[(size_t)c * T_ + s];
        if (lg > 0.f) L += lg * __expf(pmB[(size_t)c * T_ + s] - M);
    }
    const float Li = 1.0f / L;

    float* FB = F + (size_t)b * NCHUNK * T_;
    #pragma unroll
    for (int c = 0; c < NCHUNK; ++c)
        FB[(size_t)c * T_ + s] = (c >= c0) ? __expf(pmB[(size_t)c * T_ + s] - M) * Li : 0.f;
}

// ---------------------------------------------------------------------------
// Kernel B3 (MFMA, register-resident, pipelined, 8-way split-s): out = P @ V,
// P = E'[t,s] * f[s],  f = F[b][ti][s] (fully precooked).  Prologue is now a
// trivial contiguous float4 copy of F row -> LDS (~1 us), not a stats
// recompute.  Inner loop: bf16->f32, one mul, hw cvt -- no exp, no mask.
// Block = 512 thr = 8 waves, one 16-row t-tile; wave w handles chunks
// ci ≡ w (mod 8); ci+8's S prefetched into registers while ci computes.
// Padded (stride-132) LDS reduction to avoid 4-way bank conflicts.
// ---------------------------------------------------------------------------
#define RST 132
__global__ __launch_bounds__(512) void out_kernel(
    const u16* __restrict__ S, const u16* __restrict__ Vt,
    const float* __restrict__ F, float* __restrict__ out)
{
    const int b  = blockIdx.y;
    const int tb = (int)(gridDim.x - 1 - blockIdx.x); // heavy tiles first
    const int t0 = tb * 16;
    const int ti = t0 >> 7;                           // this block's t-chunk
    const int nchunks = (t0 + 79) >> 6;               // s0 <= t0+15

    const int w    = threadIdx.x >> 6;                // 0..7: chunk split
    const int lane = threadIdx.x & 63;
    const int q    = lane >> 4, r = lane & 15;
    const int t    = t0 + r;                          // this lane's A row

    const u16* SB  = S  + (size_t)b * NSCH * T_ * 64;
    const u16* VtB = Vt + (size_t)b * H_ * T_;

    __shared__ float fs[T_];                          // 8 KB column factors
    __shared__ float red[8][16 * RST];                // 67.6 KB, padded rows

    floatx4 acc[8] = {};
    short8 sc[2];

    int ci = w;
    if (ci < nchunks) {                               // issue first S loads
        const u16* Sc = SB + ((size_t)ci * T_ + t) * 64;  // (hide under prologue)
        sc[0] = *(const short8*)&Sc[q * 8];
        sc[1] = *(const short8*)&Sc[32 + q * 8];
    }

    // ---- prologue: contiguous copy of cooked factors F[b][ti][*] -> LDS --
    const int smax = 64 * nchunks;
    const float* FB = F + ((size_t)b * NCHUNK + ti) * T_;
    for (int i = threadIdx.x * 4; i < smax; i += 2048)
        *(float4*)&fs[i] = *(const float4*)&FB[i];
    __syncthreads();

    while (ci < nchunks) {
        const int s0 = ci * 64;
        const int cn = ci + 8;

        short8 sn[2];
        if (cn < nchunks) {                           // prefetch next chunk
            const u16* Sc = SB + ((size_t)cn * T_ + t) * 64;
            sn[0] = *(const short8*)&Sc[q * 8];
            sn[1] = *(const short8*)&Sc[32 + q * 8];
        }

        #pragma unroll
        for (int kk = 0; kk < 2; ++kk) {
            const int sb = s0 + kk * 32 + q * 8;      // global s base
            float fv[8];
            *(float4*)&fv[0] = *(const float4*)&fs[sb];
            *(float4*)&fv[4] = *(const float4*)&fs[sb + 4];

            short8 af;                                // P = E' * f  (no exp!)
            #pragma unroll
            for (int j = 0; j < 8; ++j)
                af[j] = (short)f2bf(bf2f((u16)sc[kk][j]) * fv[j]);

            #pragma unroll
            for (int nt = 0; nt < 8; ++nt) {
                short8 bf = *(const short8*)&VtB[(size_t)(16 * nt + r) * T_ + sb];
                acc[nt] = __builtin_amdgcn_mfma_f32_16x16x32_bf16(af, bf, acc[nt], 0, 0, 0);
            }
        }

        sc[0] = sn[0];                                // rotate pipeline regs
        sc[1] = sn[1];
        ci = cn;
    }

    #pragma unroll
    for (int nt = 0; nt < 8; ++nt)
        #pragma unroll
        for (int reg = 0; reg < 4; ++reg)
            red[w][(q * 4 + reg) * RST + 16 * nt + r] = acc[nt][reg];
    __syncthreads();

    float* outB = out + ((size_t)b * T_ + t0) * H_;
    for (int i = threadIdx.x; i < 16 * 128; i += 512) {
        const int row = i >> 7, col = i & 127;
        float sum = 0.f;
        #pragma unroll
        for (int g = 0; g < 8; ++g) sum += red[g][row * RST + col];
        outB[i] = sum;
    }
}

// ---------------------------------------------------------------------------
extern "C" void kernel_launch(void* const* d_in, const int* in_sizes, int n_in,
                              void* d_out, int out_size, void* d_ws, size_t ws_size,
                              hipStream_t stream) {
    const float* x  = (const float*)d_in[0];
    const float* Wq = (const float*)d_in[1];
    const float* Wk = (const float*)d_in[2];
    const float* Wv = (const float*)d_in[3];
    float* out = (float*)d_out;

    // workspace: S3 bf16 [B][32][T][64] (32 MB), Wt, Qb, Kb, Vt, F table.
    u16*   Sb   = (u16*)d_ws;                          // 32 MB
    u16*   Wt   = Sb + (size_t)B_ * T_ * T_;           // 0.75 MB
    u16*   Qb   = Wt + (size_t)3 * H_ * C_;            // 2 MB
    u16*   Kb   = Qb + (size_t)B_ * T_ * H_;           // 2 MB
    u16*   Vt   = Kb + (size_t)B_ * T_ * H_;           // 2 MB
    float* F    = (float*)(Vt + (size_t)B_ * T_ * H_); // 2 MB
    // total ~41 MB

    // d_out staging: pm/pl (1 MB) written by scores, read only by stats_f
    // (which runs before out_kernel overwrites d_out).  No race.
    float* pm = (float*)d_out;
    float* pl = pm + (size_t)B_ * NCHUNK * T_;

    convert_w_kernel <<<dim3(C_ / 64, H_ / 64, 3), dim3(256), 0, stream>>>(Wq, Wk, Wv, Wt);
    qkv_gemm_kernel  <<<dim3(B_ * T_ / 64, 3),     dim3(256), 0, stream>>>(x, Wt, Qb, Kb, Vt);
    scores_kernel    <<<dim3(16, 16, B_),          dim3(256), 0, stream>>>(Qb, Kb, Sb, pm, pl);
    stats_f_kernel   <<<dim3(B_ * T_ / 256),       dim3(256), 0, stream>>>(pm, pl, F);
    out_kernel       <<<dim3(T_ / 16, B_),         dim3(512), 0, stream>>>(Sb, Vt, F, out);
}

// Round 4
// 161.696 us; speedup vs baseline: 1.1439x; 1.0811x over previous
//
#include <hip/hip_runtime.h>
#include <hip/hip_bf16.h>
#include <math.h>

#define B_ 4
#define T_ 2048
#define C_ 1024
#define H_ 128
#define RCHUNK 128                 // rows per stats chunk == scores t-tile
#define NCHUNK (T_ / RCHUNK)       // 16 chunks
#define NSCH 32                    // number of 64-wide s-chunks (T/64)

typedef unsigned short u16;
typedef unsigned int   u32;
typedef short short8  __attribute__((ext_vector_type(8)));  // 8 bf16 = 4 VGPRs
typedef short short4v __attribute__((ext_vector_type(4)));  // 8B
typedef float floatx4 __attribute__((ext_vector_type(4)));  // MFMA C/D

// fp32 -> bf16 RNE via hardware cvt (v_cvt_pk_bf16_f32), not bit-twiddle
__device__ __forceinline__ u16 f2bf(float f) {
    __hip_bfloat16 h = __float2bfloat16(f);
    union { __hip_bfloat16 h; u16 u; } v; v.h = h; return v.u;
}
// bf16 -> fp32
__device__ __forceinline__ float bf2f(u16 h) {
    union { u32 u; float f; } v; v.u = ((u32)h) << 16;
    return v.f;
}

// ---------------------------------------------------------------------------
// Kernel A1: W [C][H] fp32 -> Wt [3][H][C] bf16 (transposed for MFMA B-frags).
// ---------------------------------------------------------------------------
__global__ __launch_bounds__(256) void convert_w_kernel(
    const float* __restrict__ Wq, const float* __restrict__ Wk,
    const float* __restrict__ Wv, u16* __restrict__ Wt)
{
    const int k0 = blockIdx.x * 64, n0 = blockIdx.y * 64, widx = blockIdx.z;
    const float* W = (widx == 0) ? Wq : (widx == 1) ? Wk : Wv;

    __shared__ float ts[64][68];                // +4 pad
    for (int i = threadIdx.x; i < 64 * 16; i += 256) {
        int r = i >> 4, c4 = i & 15;
        float4 v = *(const float4*)&W[(size_t)(k0 + r) * H_ + n0 + c4 * 4];
        ts[r][c4 * 4 + 0] = v.x; ts[r][c4 * 4 + 1] = v.y;
        ts[r][c4 * 4 + 2] = v.z; ts[r][c4 * 4 + 3] = v.w;
    }
    __syncthreads();
    for (int i = threadIdx.x; i < 64 * 16; i += 256) {
        int n = i >> 4, k4 = i & 15;
        short4v o;
        #pragma unroll
        for (int j = 0; j < 4; ++j) o[j] = (short)f2bf(ts[k4 * 4 + j][n]);
        *(short4v*)&Wt[(size_t)widx * H_ * C_ + (size_t)(n0 + n) * C_ + k0 + k4 * 4] = o;
    }
}

// ---------------------------------------------------------------------------
// Kernel A2 (MFMA): QKV projection, A staged straight from fp32 x with
// in-register bf16 conversion.  grid (M/64, 3); block 256 = 4 waves;
// tile 64(m) x 128(n); BK=128.  widx 0/1 -> Q,K row-major; widx 2 -> V
// stored TRANSPOSED directly (C/D gives 4 consecutive t per lane).
// ---------------------------------------------------------------------------
__global__ __launch_bounds__(256) void qkv_gemm_kernel(
    const float* __restrict__ x, const u16* __restrict__ Wt,
    u16* __restrict__ Qb, u16* __restrict__ Kb, u16* __restrict__ Vt)
{
    const int m0   = blockIdx.x * 64;
    const int widx = blockIdx.y;
    const u16* Wg = Wt + (size_t)widx * H_ * C_;

    __shared__ u16 As[64 * 136];                // 17.4 KB
    __shared__ u16 Bs[128 * 136];               // 34.8 KB

    const int w    = threadIdx.x >> 6;          // wave -> m rows [16w,16w+16)
    const int lane = threadIdx.x & 63;
    const int q    = lane >> 4, r = lane & 15;

    floatx4 acc[8] = {};                        // 16(m) x 128(n)

    for (int k0 = 0; k0 < C_; k0 += 128) {
        for (int i = threadIdx.x; i < 64 * 16; i += 256) {
            int rr = i >> 4, c = i & 15;
            const float* xg = &x[(size_t)(m0 + rr) * C_ + k0 + c * 8];
            float4 a = *(const float4*)xg;
            float4 b = *(const float4*)(xg + 4);
            short8 o;
            o[0]=(short)f2bf(a.x); o[1]=(short)f2bf(a.y);
            o[2]=(short)f2bf(a.z); o[3]=(short)f2bf(a.w);
            o[4]=(short)f2bf(b.x); o[5]=(short)f2bf(b.y);
            o[6]=(short)f2bf(b.z); o[7]=(short)f2bf(b.w);
            *(short8*)&As[rr * 136 + c * 8] = o;
        }
        for (int i = threadIdx.x; i < 128 * 16; i += 256) {
            int rr = i >> 4, c = i & 15;
            *(float4*)&Bs[rr * 136 + c * 8] =
                *(const float4*)&Wg[(size_t)rr * C_ + k0 + c * 8];
        }
        __syncthreads();

        #pragma unroll
        for (int kk = 0; kk < 4; ++kk) {
            short8 af = *(const short8*)&As[(16 * w + r) * 136 + kk * 32 + q * 8];
            #pragma unroll
            for (int nt = 0; nt < 8; ++nt) {
                short8 bf = *(const short8*)&Bs[(16 * nt + r) * 136 + kk * 32 + q * 8];
                acc[nt] = __builtin_amdgcn_mfma_f32_16x16x32_bf16(af, bf, acc[nt], 0, 0, 0);
            }
        }
        __syncthreads();
    }

    if (widx == 2) {
        const int bb  = m0 / T_;                // 64-row tile never spans b
        const int tt0 = (m0 - bb * T_) + 16 * w + q * 4;
        #pragma unroll
        for (int nt = 0; nt < 8; ++nt) {
            short4v o;
            #pragma unroll
            for (int reg = 0; reg < 4; ++reg) o[reg] = (short)f2bf(acc[nt][reg]);
            *(short4v*)&Vt[((size_t)bb * H_ + 16 * nt + r) * T_ + tt0] = o;
        }
    } else {
        u16* dst = (widx == 0) ? Qb : Kb;
        #pragma unroll
        for (int nt = 0; nt < 8; ++nt)
            #pragma unroll
            for (int reg = 0; reg < 4; ++reg) {
                int mm = m0 + 16 * w + q * 4 + reg;     // C/D row map
                int nn = 16 * nt + r;                   // C/D col map
                dst[(size_t)mm * H_ + nn] = f2bf(acc[nt][reg]);
            }
    }
}

// ---------------------------------------------------------------------------
// Kernel B1 (MFMA, fused stats): 128x128 tile of S = scale * Q·K^T (lower
// triangle).  Stores E' = exp(S - M_chunk) (masked entries -> 0) as BF16 in
// chunk-tiled layout S3[b][s/64][t][64].  Column stats per 128-row chunk:
// pm = M_chunk (scaled max), pl = sum of exp(S - M_chunk) over valid rows.
// ---------------------------------------------------------------------------
__global__ __launch_bounds__(256) void scores_kernel(
    const u16* __restrict__ Qb, const u16* __restrict__ Kb,
    u16* __restrict__ S, float* __restrict__ pm, float* __restrict__ pl)
{
    const int si = blockIdx.x;                  // 0..15 (s tile, 128 wide)
    const int ti = blockIdx.y;                  // 0..15 (t tile, 128 tall)
    const int b  = blockIdx.z;
    if (si > ti) return;                        // strictly-upper tiles unused
    const int t0 = ti * 128, s0 = si * 128;
    const bool diag = (si == ti);               // tile touches the diagonal

    __shared__ u16 smem[2 * 128 * 136];         // 69.6 KB: Qs | Ks, then reused
    u16* Qs = smem;
    u16* Ks = smem + 128 * 136;

    const u16* Qg = Qb + ((size_t)b * T_ + t0) * H_;
    const u16* Kg = Kb + ((size_t)b * T_ + s0) * H_;

    for (int i = threadIdx.x; i < 128 * 16; i += 256) {
        int rr = i >> 4, c = i & 15;
        *(float4*)&Qs[rr * 136 + c * 8] = *(const float4*)&Qg[(size_t)rr * H_ + c * 8];
        *(float4*)&Ks[rr * 136 + c * 8] = *(const float4*)&Kg[(size_t)rr * H_ + c * 8];
    }
    __syncthreads();

    const int w    = threadIdx.x >> 6;          // wave -> t rows [32w,32w+32)
    const int lane = threadIdx.x & 63;
    const int q    = lane >> 4, r = lane & 15;

    floatx4 acc[2][8] = {};                     // [m-tile][n-tile] 32t x 128s
    #pragma unroll
    for (int kk = 0; kk < 4; ++kk) {
        short8 a0 = *(const short8*)&Qs[(32 * w +      r) * 136 + kk * 32 + q * 8];
        short8 a1 = *(const short8*)&Qs[(32 * w + 16 + r) * 136 + kk * 32 + q * 8];
        #pragma unroll
        for (int nt = 0; nt < 8; ++nt) {
            short8 bf = *(const short8*)&Ks[(16 * nt + r) * 136 + kk * 32 + q * 8];
            acc[0][nt] = __builtin_amdgcn_mfma_f32_16x16x32_bf16(a0, bf, acc[0][nt], 0, 0, 0);
            acc[1][nt] = __builtin_amdgcn_mfma_f32_16x16x32_bf16(a1, bf, acc[1][nt], 0, 0, 0);
        }
    }
    __syncthreads();                            // everyone done with Qs/Ks

    // ---- reuse smem: bf16 E' tile [128][136] + reduction arrays ---------
    u16*   tile = smem;                         // 34.8 KB
    float* redm = (float*)(smem + 128 * 136);   // [16][128] = 8 KB
    float* redl = redm + 16 * 128;              // [16][128] = 8 KB
    float* Mrow = redl + 16 * 128;              // [128]     = 0.5 KB

    const float scale = 0.08838834764831845f;   // 1/sqrt(128)

    // phase 1: per-thread-group raw column max from accumulators
    #pragma unroll
    for (int nt = 0; nt < 8; ++nt) {
        const int sl = 16 * nt + r;             // local col (C/D col map)
        float mx = -INFINITY;
        #pragma unroll
        for (int mt = 0; mt < 2; ++mt)
            #pragma unroll
            for (int reg = 0; reg < 4; ++reg) {
                const int tl = 32 * w + 16 * mt + q * 4 + reg;
                const bool vl = (!diag) || (tl >= sl);
                mx = fmaxf(mx, vl ? acc[mt][nt][reg] : -INFINITY);
            }
        redm[(4 * w + q) * 128 + sl] = mx;
    }
    __syncthreads();

    // phase 2a: combine 16 row-groups -> scaled chunk max M; publish pm+Mrow
    if (threadIdx.x < 128) {
        const int c = threadIdx.x;
        float M = -INFINITY;
        #pragma unroll
        for (int g = 0; g < 16; ++g) M = fmaxf(M, redm[g * 128 + c]);
        M *= scale;
        Mrow[c] = M;
        pm[((size_t)b * NCHUNK + ti) * T_ + s0 + c] = M;
    }
    __syncthreads();

    // phase 3: single exp pass -> E' tile + per-group sums
    #pragma unroll
    for (int nt = 0; nt < 8; ++nt) {
        const int sl = 16 * nt + r;
        const float M = Mrow[sl];
        float sm = 0.f;
        #pragma unroll
        for (int mt = 0; mt < 2; ++mt)
            #pragma unroll
            for (int reg = 0; reg < 4; ++reg) {
                const int tl = 32 * w + 16 * mt + q * 4 + reg;
                const bool vl = (!diag) || (tl >= sl);
                const float e = vl ? __expf(acc[mt][nt][reg] * scale - M) : 0.f;
                sm += e;
                tile[tl * 136 + sl] = f2bf(e);
            }
        redl[(4 * w + q) * 128 + sl] = sm;
    }
    __syncthreads();

    // phase 2b: L = plain sum of group sums (all relative to same M) -> pl
    if (threadIdx.x < 128) {
        const int c = threadIdx.x;
        float L = 0.f;
        #pragma unroll
        for (int g = 0; g < 16; ++g) L += redl[g * 128 + c];
        pl[((size_t)b * NCHUNK + ti) * T_ + s0 + c] = L;
    }

    // two contiguous 16 KB chunk stores: S3[b][2si+cc][t0..t0+128)[0..64)
    for (int i = threadIdx.x; i < 128 * 16; i += 256) {
        int tl = i >> 4, cc = (i >> 3) & 1, c8 = i & 7;
        u16* Sg = S + (((size_t)b * NSCH + 2 * si + cc) * T_ + t0 + tl) * 64;
        *(float4*)&Sg[c8 * 8] = *(float4*)&tile[tl * 136 + cc * 64 + c8 * 8];
    }
}

// ---------------------------------------------------------------------------
// Kernel B2: cook the full factor table ONCE.  For each (b,s):
//   M[s] = max_c pm[c][s],  L[s] = sum_c pl[c][s]*exp(pm[c][s]-M)
//   F[b][c][s] = exp(pm[c][s]-M[s]) / L[s]   (0 for chunks below diagonal)
// 32 blocks; the serial chunk-load chain is paid once per (b,s).
// ---------------------------------------------------------------------------
__global__ __launch_bounds__(256) void stats_f_kernel(
    const float* __restrict__ pm, const float* __restrict__ pl,
    float* __restrict__ F)
{
    const int idx = blockIdx.x * 256 + threadIdx.x;   // b*T + s
    const int b = idx >> 11, s = idx & (T_ - 1);
    const int c0 = s >> 7;                            // first chunk with t>=s
    const float* pmB = pm + (size_t)b * NCHUNK * T_;
    const float* plB = pl + (size_t)b * NCHUNK * T_;

    float M = -INFINITY;
    for (int c = c0; c < NCHUNK; ++c)
        M = fmaxf(M, pmB[(size_t)c * T_ + s]);
    float L = 0.f;
    for (int c = c0; c < NCHUNK; ++c) {
        const float lg = plB[(size_t)c * T_ + s];
        if (lg > 0.f) L += lg * __expf(pmB[(size_t)c * T_ + s] - M);
    }
    const float Li = 1.0f / L;

    float* FB = F + (size_t)b * NCHUNK * T_;
    #pragma unroll
    for (int c = 0; c < NCHUNK; ++c)
        FB[(size_t)c * T_ + s] = (c >= c0) ? __expf(pmB[(size_t)c * T_ + s] - M) * Li : 0.f;
}

// ---------------------------------------------------------------------------
// Kernel B3 (MFMA, PAIRED-TILE balanced): out = P @ V, P = E'[t,s]*f[s].
// Old grid (128,4) had per-CU work spread 2..64 chunk-units (2 blocks/CU,
// same-tb blocks adjacent): runtime = heaviest CU (~1.9x mean).  Now block
// i owns the COMPLEMENTARY pair of 16-row t-tiles {i, 127-i}: every block
// does exactly ncA+ncB = 33 chunk-units.  8 waves interleave over the union
// chunk list (k == w mod 8); the A/B branch is wave-uniform and each branch
// statically indexes its own acc array (no scratch).  Grid 256 = 1 block/CU
// (LDS 82.5 KB), perfectly uniform.  Inner loop unchanged: E'*f, no exp.
// ---------------------------------------------------------------------------
#define RST 132
__global__ __launch_bounds__(512) void out_kernel(
    const u16* __restrict__ S, const u16* __restrict__ Vt,
    const float* __restrict__ F, float* __restrict__ out)
{
    const int b   = blockIdx.y;
    const int i   = blockIdx.x;                       // 0..63
    const int t0A = i * 16;                           // light tile
    const int t0B = (127 - i) * 16;                   // heavy tile
    const int ncA = (t0A + 79) >> 6;                  // chunks: s0 <= t0+15
    const int ncB = (t0B + 79) >> 6;
    const int nct = ncA + ncB;                        // == 33 for all i

    const int w    = threadIdx.x >> 6;                // 0..7: union-chunk split
    const int lane = threadIdx.x & 63;
    const int q    = lane >> 4, r = lane & 15;
    const int tA   = t0A + r, tB = t0B + r;           // lane's A rows

    const u16* SB  = S  + (size_t)b * NSCH * T_ * 64;
    const u16* VtB = Vt + (size_t)b * H_ * T_;

    __shared__ float fsA[T_], fsB[T_];                // 16 KB cooked factors
    __shared__ float red[8][16 * RST];                // 66 KB, padded rows

    floatx4 accA[8] = {}, accB[8] = {};
    short8 sc[2];

    int kcur = w;                                     // issue first S loads
    {                                                 // (hide under prologue)
        const bool A = kcur < ncA;
        const int ci = A ? kcur : kcur - ncA;         // kcur < nct always
        const u16* Sc = SB + ((size_t)ci * T_ + (A ? tA : tB)) * 64;
        sc[0] = *(const short8*)&Sc[q * 8];
        sc[1] = *(const short8*)&Sc[32 + q * 8];
    }

    // ---- prologue: contiguous copy of cooked F rows for both tiles -------
    const int tiA = t0A >> 7, tiB = t0B >> 7;
    const float* FA = F + ((size_t)b * NCHUNK + tiA) * T_;
    const float* FBg = F + ((size_t)b * NCHUNK + tiB) * T_;
    for (int idx = threadIdx.x * 4; idx < 64 * ncA; idx += 2048)
        *(float4*)&fsA[idx] = *(const float4*)&FA[idx];
    for (int idx = threadIdx.x * 4; idx < 64 * ncB; idx += 2048)
        *(float4*)&fsB[idx] = *(const float4*)&FBg[idx];
    __syncthreads();

    // inlined twice with static acc/fs bindings (no dynamic reg indexing)
    auto body = [&](floatx4 (&acc)[8], const float* fsrow, int s0) {
        #pragma unroll
        for (int kk = 0; kk < 2; ++kk) {
            const int sb = s0 + kk * 32 + q * 8;      // global s base
            float fv[8];
            *(float4*)&fv[0] = *(const float4*)&fsrow[sb];
            *(float4*)&fv[4] = *(const float4*)&fsrow[sb + 4];
            short8 af;                                // P = E' * f  (no exp)
            #pragma unroll
            for (int j = 0; j < 8; ++j)
                af[j] = (short)f2bf(bf2f((u16)sc[kk][j]) * fv[j]);
            #pragma unroll
            for (int nt = 0; nt < 8; ++nt) {
                short8 bf = *(const short8*)&VtB[(size_t)(16 * nt + r) * T_ + sb];
                acc[nt] = __builtin_amdgcn_mfma_f32_16x16x32_bf16(af, bf, acc[nt], 0, 0, 0);
            }
        }
    };

    while (kcur < nct) {
        const int knx = kcur + 8;
        short8 sn[2];
        if (knx < nct) {                              // prefetch next chunk
            const bool A = knx < ncA;
            const int ci = A ? knx : knx - ncA;
            const u16* Sc = SB + ((size_t)ci * T_ + (A ? tA : tB)) * 64;
            sn[0] = *(const short8*)&Sc[q * 8];
            sn[1] = *(const short8*)&Sc[32 + q * 8];
        }

        if (kcur < ncA) body(accA, fsA, kcur * 64);           // wave-uniform
        else            body(accB, fsB, (kcur - ncA) * 64);

        sc[0] = sn[0];                                // rotate pipeline regs
        sc[1] = sn[1];
        kcur = knx;
    }

    // ---- epilogue pass 1: tile A -----------------------------------------
    #pragma unroll
    for (int nt = 0; nt < 8; ++nt)
        #pragma unroll
        for (int reg = 0; reg < 4; ++reg)
            red[w][(q * 4 + reg) * RST + 16 * nt + r] = accA[nt][reg];
    __syncthreads();

    float* outA = out + ((size_t)b * T_ + t0A) * H_;
    for (int idx = threadIdx.x; idx < 16 * 128; idx += 512) {
        const int row = idx >> 7, col = idx & 127;
        float sum = 0.f;
        #pragma unroll
        for (int g = 0; g < 8; ++g) sum += red[g][row * RST + col];
        outA[idx] = sum;
    }
    __syncthreads();                                  // red reuse barrier

    // ---- epilogue pass 2: tile B -----------------------------------------
    #pragma unroll
    for (int nt = 0; nt < 8; ++nt)
        #pragma unroll
        for (int reg = 0; reg < 4; ++reg)
            red[w][(q * 4 + reg) * RST + 16 * nt + r] = accB[nt][reg];
    __syncthreads();

    float* outB = out + ((size_t)b * T_ + t0B) * H_;
    for (int idx = threadIdx.x; idx < 16 * 128; idx += 512) {
        const int row = idx >> 7, col = idx & 127;
        float sum = 0.f;
        #pragma unroll
        for (int g = 0; g < 8; ++g) sum += red[g][row * RST + col];
        outB[idx] = sum;
    }
}

// ---------------------------------------------------------------------------
extern "C" void kernel_launch(void* const* d_in, const int* in_sizes, int n_in,
                              void* d_out, int out_size, void* d_ws, size_t ws_size,
                              hipStream_t stream) {
    const float* x  = (const float*)d_in[0];
    const float* Wq = (const float*)d_in[1];
    const float* Wk = (const float*)d_in[2];
    const float* Wv = (const float*)d_in[3];
    float* out = (float*)d_out;

    // workspace: S3 bf16 [B][32][T][64] (32 MB), Wt, Qb, Kb, Vt, F table.
    u16*   Sb   = (u16*)d_ws;                          // 32 MB
    u16*   Wt   = Sb + (size_t)B_ * T_ * T_;           // 0.75 MB
    u16*   Qb   = Wt + (size_t)3 * H_ * C_;            // 2 MB
    u16*   Kb   = Qb + (size_t)B_ * T_ * H_;           // 2 MB
    u16*   Vt   = Kb + (size_t)B_ * T_ * H_;           // 2 MB
    float* F    = (float*)(Vt + (size_t)B_ * T_ * H_); // 2 MB
    // total ~41 MB

    // d_out staging: pm/pl (1 MB) written by scores, read only by stats_f
    // (which runs before out_kernel overwrites d_out).  No race.
    float* pm = (float*)d_out;
    float* pl = pm + (size_t)B_ * NCHUNK * T_;

    convert_w_kernel <<<dim3(C_ / 64, H_ / 64, 3), dim3(256), 0, stream>>>(Wq, Wk, Wv, Wt);
    qkv_gemm_kernel  <<<dim3(B_ * T_ / 64, 3),     dim3(256), 0, stream>>>(x, Wt, Qb, Kb, Vt);
    scores_kernel    <<<dim3(16, 16, B_),          dim3(256), 0, stream>>>(Qb, Kb, Sb, pm, pl);
    stats_f_kernel   <<<dim3(B_ * T_ / 256),       dim3(256), 0, stream>>>(pm, pl, F);
    out_kernel       <<<dim3(64, B_),              dim3(512), 0, stream>>>(Sb, Vt, F, out);
}